// Round 7
// baseline (98.001 us; speedup 1.0000x reference)
//
#include <hip/hip_runtime.h>

#define N_INPUTS 16384
#define N_DET    65536
#define KD       32
#define BATCH    32
#define SLICES   16                        // det slices; slice+16*batch -> XCD slice%8
#define DPB      (N_DET / SLICES)          // 4096 detectors per block
#define THREADS  1024                      // 16 waves; 66 KB LDS -> 2 blocks/CU

__device__ __forceinline__ float max3f(float a, float b, float c) {
    return fmaxf(fmaxf(a, b), c);          // fuses to v_max3_f32
}

// ---------------------------------------------------------------------------
// One block = (ONE batch row, 64 KB LDS) x (one detector slice). 66 KB total
// LDS -> 2 blocks/CU = 32 waves/CU (8/SIMD, enforced by launch_bounds) --
// R6 was latency-bound at 4 waves/SIMD with both pipes under 40% busy, so
// occupancy is the lever, not burst depth. Per detector: 32 random
// ds_read_b32 gathers (64 req/32 banks, ~half the conflict queue of R6's
// b64), winner slot via per-half max3-tree + equality bitmask combined with
// '>=' (exact first-max tie-break; duplicate ids tie -> ctz picks first
// slot, other slot flagged loser, matching jnp.argmax). Loser flags: 1 bit
// per input in a 2 KB LDS array via unpredicated fire-and-forget ds_or
// (winner slot contributes 0 -> no exec-mask dance, no races). Ids are kept
// packed 2x16-bit (16 VGPRs) to fit the 64-VGPR budget of 8 waves/SIMD.
// ---------------------------------------------------------------------------
__global__ __launch_bounds__(THREADS, 8) void inhibit(const float* __restrict__ x,
                                                      const int* __restrict__ det,
                                                      unsigned* __restrict__ pm) {
    __shared__ float    xs[N_INPUTS];        // 64 KB: x[batch][*]
    __shared__ unsigned fl[N_INPUTS / 32];   // 2 KB: loser bit per input

    const int slice = blockIdx.x;
    const int batch = blockIdx.y;
    const int tid   = threadIdx.x;

    if (tid < N_INPUTS / 32) fl[tid] = 0u;

    // stage row: 4 coalesced float4 per thread
    const float4* xr  = (const float4*)(x + (size_t)batch * N_INPUTS);
    float4*       xs4 = (float4*)xs;
#pragma unroll
    for (int k = 0; k < N_INPUTS / 4 / THREADS; ++k)
        xs4[tid + k * THREADS] = xr[tid + k * THREADS];
    __syncthreads();

    const int4* det4 = (const int4*)det;
#pragma unroll 1
    for (int j = 0; j < DPB / THREADS; ++j) {      // 4 detectors per thread
        const int   d    = slice * DPB + j * THREADS + tid;
        const int4* drow = det4 + (size_t)d * 8;

        unsigned pk[16];                           // ids packed 2x16-bit
        float    m = 0.f;                          // set by half 0
        unsigned e = 0u;
#pragma unroll
        for (int h = 0; h < 2; ++h) {
            int4 r0 = drow[4 * h + 0], r1 = drow[4 * h + 1];
            int4 r2 = drow[4 * h + 2], r3 = drow[4 * h + 3];
            int ids[16] = { r0.x, r0.y, r0.z, r0.w, r1.x, r1.y, r1.z, r1.w,
                            r2.x, r2.y, r2.z, r2.w, r3.x, r3.y, r3.z, r3.w };
            float v[16];                           // 16-deep ds_read_b32 burst
#pragma unroll
            for (int s = 0; s < 16; ++s) v[s] = xs[ids[s]];
#pragma unroll
            for (int p = 0; p < 8; ++p)
                pk[h * 8 + p] = (unsigned)ids[2 * p] | ((unsigned)ids[2 * p + 1] << 16);

            // max3 tree (exact: returns an input bit-for-bit)
            float t0 = max3f(v[0], v[1], v[2]),  t1 = max3f(v[3], v[4], v[5]);
            float t2 = max3f(v[6], v[7], v[8]),  t3 = max3f(v[9], v[10], v[11]);
            float t4 = max3f(v[12], v[13], v[14]);
            float mh = fmaxf(max3f(t0, t1, t2), max3f(t3, t4, v[15]));

            unsigned f = 0u;                       // equality bitmask vs half max
#pragma unroll
            for (int s = 0; s < 16; ++s) f |= (v[s] == mh) ? (1u << s) : 0u;

            if (h == 0) { m = mh; e = f; }
            else {
                e = (m >= mh ? e : 0u) | (mh >= m ? (f << 16) : 0u);
                m = fmaxf(m, mh);
            }
        }
        const int      s0 = __builtin_ctz(e);      // first-max slot
        const unsigned wm = 1u << s0;
#pragma unroll
        for (int k = 0; k < 16; ++k) {             // unpredicated or; winner adds 0
            unsigned id0 = pk[k] & 0xFFFFu;
            unsigned id1 = pk[k] >> 16;
            unsigned l0  = ((wm >> (2 * k)) & 1u) ^ 1u;
            unsigned l1  = ((wm >> (2 * k + 1)) & 1u) ^ 1u;
            atomicOr(&fl[id0 >> 5], l0 << (id0 & 31));
            atomicOr(&fl[id1 >> 5], l1 << (id1 & 31));
        }
    }
    __syncthreads();

    // write 2 KB partial loser mask (u32 granularity)
    if (tid < N_INPUTS / 32)
        pm[((size_t)(batch * SLICES + slice)) * (N_INPUTS / 32) + tid] = fl[tid];
}

// ---------------------------------------------------------------------------
// out[b][i] = 1.0 iff bit i clear in OR of the batch's 16 slice masks.
// ---------------------------------------------------------------------------
__global__ __launch_bounds__(256) void finalize(const unsigned* __restrict__ pm,
                                                float* __restrict__ out) {
    const int gid = blockIdx.x * 256 + threadIdx.x;   // 0 .. B*N_INPUTS-1
    const int b   = gid >> 14;
    const int i   = gid & (N_INPUTS - 1);
    unsigned acc = 0;
#pragma unroll
    for (int s = 0; s < SLICES; ++s)
        acc |= pm[((b * SLICES + s) << 9) + (i >> 5)]; // 512 u32 per partial
    out[gid] = ((acc >> (i & 31)) & 1u) ? 0.0f : 1.0f;
}

extern "C" void kernel_launch(void* const* d_in, const int* in_sizes, int n_in,
                              void* d_out, int out_size, void* d_ws, size_t ws_size,
                              hipStream_t stream) {
    const float* x   = (const float*)d_in[0];          // [B, N_INPUTS] f32
    const int*   det = (const int*)d_in[1];            // [N_DET, K] i32
    unsigned*    pm  = (unsigned*)d_ws;                // 1 MB partial masks

    dim3 grid(SLICES, BATCH);
    inhibit<<<grid, THREADS, 0, stream>>>(x, det, pm);
    finalize<<<BATCH * N_INPUTS / 256, 256, 0, stream>>>(pm, (float*)d_out);
}